// Round 6
// baseline (87.501 us; speedup 1.0000x reference)
//
#include <hip/hip_runtime.h>
#include <hip/hip_bf16.h>

#define N_NODES 4096
#define IN_DIMC 512
#define NHEADS 4
#define DHEAD 64
#define OUT_COLS 256  // NHEADS*DHEAD
#define HP_HEAD_BYTES (N_NODES * DHEAD * 2)  // 512 KB per head

typedef __attribute__((ext_vector_type(8))) short short8;
typedef __attribute__((ext_vector_type(4))) float f32x4;

__device__ __forceinline__ short bf16b(float x) {
    return __builtin_bit_cast(short, __float2bfloat16(x));
}

__device__ __forceinline__ void gload_lds16(const void* g, void* l) {
    __builtin_amdgcn_global_load_lds((const __attribute__((address_space(1))) void*)g,
                                     (__attribute__((address_space(3))) void*)l,
                                     16, 0, 0);
}

// ---- Kernel A (fused): h = features @ weights; epilogue emits packed hP +
//      exp tables E1=exp(s1), F1=exp(0.2 s1), E2=exp(s2), F2=exp(0.2 s2) ----
// grid (128, 4), block 256. Tile 32(M=nodes) x 64(N=d)=one head, BK=32.
// hP layout (per head): (d, j) -> 16B-slot ((g*4 + d/16)*64 + q*16 + d%16),
// elem j%8 inside; g = j/32, q = (j%32)/8.  (= MFMA B-frag order, lane-linear)
__global__ __launch_bounds__(256) void k_gemm_fused(
    const float* __restrict__ A, const float* __restrict__ W,
    const float* __restrict__ att,
    char* __restrict__ hP, float* __restrict__ E1, float* __restrict__ F1,
    float* __restrict__ E2, float* __restrict__ F2)
{
    __shared__ float As[32][36];   // A^T tile: As[k][m], padded
    __shared__ float Bs[32][68];   // Bs[k][n], padded
    __shared__ float ht[64][33];   // h tile transposed: ht[d][node], padded
    const int m0 = blockIdx.x * 32;
    const int head = blockIdx.y;
    const int n0 = head * 64;
    const int t = (int)threadIdx.x;
    const int tm = t & 7, tn = t >> 3;   // 8 x 32
    float acc[4][2] = {};
    for (int k0 = 0; k0 < IN_DIMC; k0 += 32) {
        {
            const int r = t >> 3, kc = (t & 7) << 2;
            float4 v0 = *(const float4*)(A + (size_t)(m0 + r) * IN_DIMC + k0 + kc);
            As[kc + 0][r] = v0.x; As[kc + 1][r] = v0.y; As[kc + 2][r] = v0.z; As[kc + 3][r] = v0.w;
            const int rb = t >> 4, nc = (t & 15) << 2;
            float4 w0 = *(const float4*)(W + (size_t)(k0 + rb) * OUT_COLS + n0 + nc);
            float4 w1 = *(const float4*)(W + (size_t)(k0 + rb + 16) * OUT_COLS + n0 + nc);
            *(float4*)&Bs[rb][nc] = w0;
            *(float4*)&Bs[rb + 16][nc] = w1;
        }
        __syncthreads();
        #pragma unroll
        for (int kk = 0; kk < 32; ++kk) {
            const f32x4 a = *(const f32x4*)&As[kk][tm << 2];
            const float b0 = Bs[kk][tn * 2], b1 = Bs[kk][tn * 2 + 1];
            #pragma unroll
            for (int i = 0; i < 4; ++i) {
                acc[i][0] = fmaf(a[i], b0, acc[i][0]);
                acc[i][1] = fmaf(a[i], b1, acc[i][1]);
            }
        }
        __syncthreads();
    }
    // stage h tile (f32) in LDS: ht[d][node]
    #pragma unroll
    for (int i = 0; i < 4; ++i) {
        ht[tn * 2 + 0][(tm << 2) + i] = acc[i][0];
        ht[tn * 2 + 1][(tm << 2) + i] = acc[i][1];
    }
    __syncthreads();
    // packed hP write: thread t -> d = t>>2, qq = t&3: 8 consecutive j
    {
        const int d = t >> 2, qq = t & 3;
        short8 hv;
        #pragma unroll
        for (int k = 0; k < 8; ++k) hv[k] = bf16b(ht[d][qq * 8 + k]);
        const size_t off16 = ((size_t)(m0 >> 5) * 4 + (d >> 4)) * 64 + qq * 16 + (d & 15);
        *(short8*)(hP + (size_t)head * HP_HEAD_BYTES + off16 * 16) = hv;
    }
    // s1/s2 + exp tables: row r = t>>3 (32 nodes), part = t&7 covers 8 d
    {
        const int r = t >> 3, part = t & 7;
        float p1 = 0.f, p2 = 0.f;
        #pragma unroll
        for (int dd = 0; dd < 8; ++dd) {
            const int d = part * 8 + dd;
            const float v = ht[d][r];
            p1 = fmaf(v, att[head * 128 + d], p1);
            p2 = fmaf(v, att[head * 128 + 64 + d], p2);
        }
        p1 += __shfl_xor(p1, 1); p1 += __shfl_xor(p1, 2); p1 += __shfl_xor(p1, 4);
        p2 += __shfl_xor(p2, 1); p2 += __shfl_xor(p2, 2); p2 += __shfl_xor(p2, 4);
        if (part == 0) {
            const int idx = head * N_NODES + m0 + r;
            E1[idx] = __expf(p1);
            F1[idx] = __expf(0.2f * p1);
            E2[idx] = __expf(p2);
            F2[idx] = __expf(0.2f * p2);
        }
    }
}

// ---- Kernel C: fused masked softmax + PV, exp-free P-gen ----
// grid (256) blocks of 1024 = 16 waves = 4 heads x 4 j-segments.
// P = adj ? max(e1*E2[j], f1*F2[j]) : 0   (== exp(leaky_relu(s1+s2)) masked)
// Denominator = 5th MFMA with all-ones B. Per-wave private LDS double-buffer.
__global__ __launch_bounds__(1024, 4) void k_gat(
    const int* __restrict__ adj, const char* __restrict__ hP,
    const float* __restrict__ E1, const float* __restrict__ F1,
    const float* __restrict__ E2, const float* __restrict__ F2,
    const float* __restrict__ bias, float* __restrict__ out)
{
    __shared__ __align__(16) char stage[16 * 8192];   // 128 KB: 16 waves x 2 x 4KB
    const int i0 = blockIdx.x * 16;
    const int t = (int)threadIdx.x;
    const int w = t >> 6;
    const int head = w & 3;
    const int seg = w >> 2;              // 0..3
    const int lane = t & 63;
    const int il = lane & 15;
    const int q = lane >> 4;
    char* myStage = stage + w * 8192;
    const char* hPh = hP + (size_t)head * HP_HEAD_BYTES;
    const float e1 = E1[head * N_NODES + i0 + il];
    const float f1 = F1[head * N_NODES + i0 + il];
    const float* E2h = E2 + head * N_NODES;
    const float* F2h = F2 + head * N_NODES;
    const int* arow = adj + (size_t)(i0 + il) * N_NODES;
    f32x4 acc[5] = {{0.f,0.f,0.f,0.f},{0.f,0.f,0.f,0.f},{0.f,0.f,0.f,0.f},
                    {0.f,0.f,0.f,0.f},{0.f,0.f,0.f,0.f}};
    short8 onesv;
    #pragma unroll
    for (int e = 0; e < 8; ++e) onesv[e] = (short)0x3F80;  // bf16 1.0

    const int g0 = seg * 32;             // 32 steps of 32 j each
    // prologue batch (step 0): 2x int4 adj + 2x f4 E2 + 2x f4 F2 + 4x gload_lds
    int jb = (g0 << 5) + (q << 3);
    int4   avA = *(const int4*)(arow + jb);
    int4   avB = *(const int4*)(arow + jb + 4);
    float4 e2a = *(const float4*)(E2h + jb);
    float4 e2b = *(const float4*)(E2h + jb + 4);
    float4 f2a = *(const float4*)(F2h + jb);
    float4 f2b = *(const float4*)(F2h + jb + 4);
    #pragma unroll
    for (int dblk = 0; dblk < 4; ++dblk)
        gload_lds16(hPh + (size_t)g0 * 4096 + dblk * 1024 + lane * 16,
                    myStage + dblk * 1024);

    #pragma unroll 2
    for (int s = 0; s < 32; ++s) {
        int4 navA = avA, navB = avB;
        float4 ne2a = e2a, ne2b = e2b, nf2a = f2a, nf2b = f2b;
        if (s < 31) {
            const int jn = jb + 32;
            navA = *(const int4*)(arow + jn);
            navB = *(const int4*)(arow + jn + 4);
            ne2a = *(const float4*)(E2h + jn);
            ne2b = *(const float4*)(E2h + jn + 4);
            nf2a = *(const float4*)(F2h + jn);
            nf2b = *(const float4*)(F2h + jn + 4);
            char* ldst = myStage + ((s + 1) & 1) * 4096;
            #pragma unroll
            for (int dblk = 0; dblk < 4; ++dblk)
                gload_lds16(hPh + (size_t)(g0 + s + 1) * 4096 + dblk * 1024 + lane * 16,
                            ldst + dblk * 1024);
            // previous batch (10 ops) drained; this batch (10) stays in flight
            asm volatile("s_waitcnt vmcnt(10)" ::: "memory");
        } else {
            asm volatile("s_waitcnt vmcnt(0)" ::: "memory");
        }
        // ---- P-gen: p = adj ? max(e1*E2, f1*F2) : 0  (no exp, no denom adds) ----
        short8 afrag;
        {
            float g, hh, p;
            g = e1 * e2a.x; hh = f1 * f2a.x; p = fmaxf(g, hh);
            afrag[0] = bf16b(avA.x != 0 ? p : 0.f);
            g = e1 * e2a.y; hh = f1 * f2a.y; p = fmaxf(g, hh);
            afrag[1] = bf16b(avA.y != 0 ? p : 0.f);
            g = e1 * e2a.z; hh = f1 * f2a.z; p = fmaxf(g, hh);
            afrag[2] = bf16b(avA.z != 0 ? p : 0.f);
            g = e1 * e2a.w; hh = f1 * f2a.w; p = fmaxf(g, hh);
            afrag[3] = bf16b(avA.w != 0 ? p : 0.f);
            g = e1 * e2b.x; hh = f1 * f2b.x; p = fmaxf(g, hh);
            afrag[4] = bf16b(avB.x != 0 ? p : 0.f);
            g = e1 * e2b.y; hh = f1 * f2b.y; p = fmaxf(g, hh);
            afrag[5] = bf16b(avB.y != 0 ? p : 0.f);
            g = e1 * e2b.z; hh = f1 * f2b.z; p = fmaxf(g, hh);
            afrag[6] = bf16b(avB.z != 0 ? p : 0.f);
            g = e1 * e2b.w; hh = f1 * f2b.w; p = fmaxf(g, hh);
            afrag[7] = bf16b(avB.w != 0 ? p : 0.f);
        }
        // ---- lane-linear conflict-free ds_read + 5 MFMA (4 PV + 1 denom) ----
        const short8* fb = (const short8*)(myStage + (s & 1) * 4096);
        #pragma unroll
        for (int dblk = 0; dblk < 4; ++dblk) {
            const short8 b = fb[dblk * 64 + lane];
            acc[dblk] = __builtin_amdgcn_mfma_f32_16x16x32_bf16(afrag, b, acc[dblk], 0, 0, 0);
        }
        acc[4] = __builtin_amdgcn_mfma_f32_16x16x32_bf16(afrag, onesv, acc[4], 0, 0, 0);
        // rotate
        avA = navA; avB = navB;
        e2a = ne2a; e2b = ne2b; f2a = nf2a; f2b = nf2b;
        jb += 32;
    }

    __syncthreads();                     // loops done; repurpose stage
    float* red  = (float*)stage;                 // 12 waves x 1024 f32 (48 KB)
    float* dred = (float*)(stage + 49152);       // 12 waves x 16 f32 denoms
    if (seg > 0) {
        const int p = (w - 4) * 1024;
        #pragma unroll
        for (int r = 0; r < 4; ++r) {
            const int row = q * 4 + r;           // C/D: row=(lane>>4)*4+reg, col=lane&15
            red[p + row * 64 + 0  + il] = acc[0][r];
            red[p + row * 64 + 16 + il] = acc[1][r];
            red[p + row * 64 + 32 + il] = acc[2][r];
            red[p + row * 64 + 48 + il] = acc[3][r];
        }
        if (il == 0) {
            #pragma unroll
            for (int r = 0; r < 4; ++r)
                dred[(w - 4) * 16 + q * 4 + r] = acc[4][r];
        }
    }
    __syncthreads();
    if (seg == 0) {                      // w == head
        #pragma unroll
        for (int r = 0; r < 4; ++r) {
            const int row = q * 4 + r;
            float dsum = acc[4][r];      // own-segment denom for this row
            #pragma unroll
            for (int s = 1; s < 4; ++s)
                dsum += dred[((s - 1) * 4 + w) * 16 + row];
            const float inv = 1.0f / dsum;
            #pragma unroll
            for (int dblk = 0; dblk < 4; ++dblk) {
                float v = acc[dblk][r];
                #pragma unroll
                for (int s = 1; s < 4; ++s)
                    v += red[((s - 1) * 4 + w) * 1024 + row * 64 + dblk * 16 + il];
                out[(size_t)(i0 + row) * OUT_COLS + w * DHEAD + dblk * 16 + il] =
                    v * inv + bias[w * DHEAD + dblk * 16 + il];
            }
        }
    }
}

extern "C" void kernel_launch(void* const* d_in, const int* in_sizes, int n_in,
                              void* d_out, int out_size, void* d_ws, size_t ws_size,
                              hipStream_t stream) {
    const float* features  = (const float*)d_in[0];
    const int*   adjacency = (const int*)d_in[1];
    const float* weights   = (const float*)d_in[2];
    const float* attention = (const float*)d_in[3];
    const float* bias      = (const float*)d_in[4];
    float* out = (float*)d_out;

    char* ws = (char*)d_ws;
    char*  hP = ws;                                        // 2 MB
    float* E1 = (float*)(ws + 2u*1024*1024);               // 64 KB
    float* F1 = (float*)(ws + 2u*1024*1024 +  64u*1024);   // 64 KB
    float* E2 = (float*)(ws + 2u*1024*1024 + 128u*1024);   // 64 KB
    float* F2 = (float*)(ws + 2u*1024*1024 + 192u*1024);   // 64 KB

    k_gemm_fused<<<dim3(128, 4), 256, 0, stream>>>(features, weights, attention,
                                                   hP, E1, F1, E2, F2);
    k_gat<<<dim3(256), 1024, 0, stream>>>(adjacency, hP, E1, F1, E2, F2, bias, out);
}

// Round 7
// 58.905 us; speedup vs baseline: 1.4855x; 1.4855x over previous
//
#include <hip/hip_runtime.h>
#include <hip/hip_bf16.h>

#define N_NODES 4096
#define IN_DIMC 512
#define NHEADS 4
#define DHEAD 64
#define OUT_COLS 256  // NHEADS*DHEAD
#define HPB (N_NODES * DHEAD * 2)  // 512 KB per head

typedef __attribute__((ext_vector_type(8))) short short8;
typedef __attribute__((ext_vector_type(4))) float f32x4;

__device__ __forceinline__ short bf16b(float x) {
    return __builtin_bit_cast(short, __float2bfloat16(x));
}
__device__ __forceinline__ void gload16(const void* g, void* l) {
    __builtin_amdgcn_global_load_lds((const __attribute__((address_space(1))) void*)g,
                                     (__attribute__((address_space(3))) void*)l,
                                     16, 0, 0);
}
__device__ __forceinline__ void gload4(const void* g, void* l) {
    __builtin_amdgcn_global_load_lds((const __attribute__((address_space(1))) void*)g,
                                     (__attribute__((address_space(3))) void*)l,
                                     4, 0, 0);
}

// ---- Kernel A: fused {h-GEMM + hP/exp-table epilogue} and {adjacency bitpack} ----
// grid 1536: blocks [0,512) gemm (128 m-tiles x 4 heads); [512,1536) pack.
__global__ __launch_bounds__(256) void k_prep2(
    const float* __restrict__ A, const float* __restrict__ W,
    const float* __restrict__ att, const int* __restrict__ adj,
    char* __restrict__ hP, float* __restrict__ E1, float* __restrict__ F1,
    float* __restrict__ E2, float* __restrict__ F2,
    unsigned long long* __restrict__ bitsT)
{
    const int t = (int)threadIdx.x;
    if (blockIdx.x >= 512) {
        // ---- pack: row i per wave, 64 chunk-words, ILP 4 ----
        const int pb = (int)blockIdx.x - 512;
        const int i = pb * 4 + (t >> 6);       // 0..4095
        const int lane = t & 63;
        const int* arow = adj + (size_t)i * N_NODES;
        #pragma unroll 2
        for (int it = 0; it < 16; ++it) {
            const int c = it * 4;
            const int a0 = arow[(c + 0) * 64 + lane];
            const int a1 = arow[(c + 1) * 64 + lane];
            const int a2 = arow[(c + 2) * 64 + lane];
            const int a3 = arow[(c + 3) * 64 + lane];
            const unsigned long long m0 = __ballot(a0 != 0);
            const unsigned long long m1 = __ballot(a1 != 0);
            const unsigned long long m2 = __ballot(a2 != 0);
            const unsigned long long m3 = __ballot(a3 != 0);
            if (lane == 0) {
                bitsT[(size_t)(c + 0) * N_NODES + i] = m0;
                bitsT[(size_t)(c + 1) * N_NODES + i] = m1;
                bitsT[(size_t)(c + 2) * N_NODES + i] = m2;
                bitsT[(size_t)(c + 3) * N_NODES + i] = m3;
            }
        }
        return;
    }
    // ---- gemm: tile 32(nodes) x 64(d) = one head slice ----
    __shared__ float As[32][36];
    __shared__ float Bs[32][68];
    __shared__ float ht[64][33];
    const int m0 = ((int)blockIdx.x & 127) * 32;
    const int head = (int)blockIdx.x >> 7;
    const int n0 = head * 64;
    const int tm = t & 7, tn = t >> 3;
    float acc[4][2] = {};
    for (int k0 = 0; k0 < IN_DIMC; k0 += 32) {
        {
            const int r = t >> 3, kc = (t & 7) << 2;
            float4 v0 = *(const float4*)(A + (size_t)(m0 + r) * IN_DIMC + k0 + kc);
            As[kc + 0][r] = v0.x; As[kc + 1][r] = v0.y; As[kc + 2][r] = v0.z; As[kc + 3][r] = v0.w;
            const int rb = t >> 4, nc = (t & 15) << 2;
            float4 w0 = *(const float4*)(W + (size_t)(k0 + rb) * OUT_COLS + n0 + nc);
            float4 w1 = *(const float4*)(W + (size_t)(k0 + rb + 16) * OUT_COLS + n0 + nc);
            *(float4*)&Bs[rb][nc] = w0;
            *(float4*)&Bs[rb + 16][nc] = w1;
        }
        __syncthreads();
        #pragma unroll
        for (int kk = 0; kk < 32; ++kk) {
            const f32x4 a = *(const f32x4*)&As[kk][tm << 2];
            const float b0 = Bs[kk][tn * 2], b1 = Bs[kk][tn * 2 + 1];
            #pragma unroll
            for (int i = 0; i < 4; ++i) {
                acc[i][0] = fmaf(a[i], b0, acc[i][0]);
                acc[i][1] = fmaf(a[i], b1, acc[i][1]);
            }
        }
        __syncthreads();
    }
    #pragma unroll
    for (int i = 0; i < 4; ++i) {
        ht[tn * 2 + 0][(tm << 2) + i] = acc[i][0];
        ht[tn * 2 + 1][(tm << 2) + i] = acc[i][1];
    }
    __syncthreads();
    {   // packed hP: (d,j) -> 16B-slot ((g*4 + d/16)*64 + q*16 + d%16), g=j/32
        const int d = t >> 2, qq = t & 3;
        short8 hv;
        #pragma unroll
        for (int k = 0; k < 8; ++k) hv[k] = bf16b(ht[d][qq * 8 + k]);
        const size_t off16 = ((size_t)(m0 >> 5) * 4 + (d >> 4)) * 64 + qq * 16 + (d & 15);
        *(short8*)(hP + (size_t)head * HPB + off16 * 16) = hv;
    }
    {   // s1/s2 -> exp tables
        const int r = t >> 3, part = t & 7;
        float p1 = 0.f, p2 = 0.f;
        #pragma unroll
        for (int dd = 0; dd < 8; ++dd) {
            const int d = part * 8 + dd;
            const float v = ht[d][r];
            p1 = fmaf(v, att[head * 128 + d], p1);
            p2 = fmaf(v, att[head * 128 + 64 + d], p2);
        }
        p1 += __shfl_xor(p1, 1); p1 += __shfl_xor(p1, 2); p1 += __shfl_xor(p1, 4);
        p2 += __shfl_xor(p2, 1); p2 += __shfl_xor(p2, 2); p2 += __shfl_xor(p2, 4);
        if (part == 0) {
            const int idx = head * N_NODES + m0 + r;
            E1[idx] = __expf(p1);
            F1[idx] = __expf(0.2f * p1);
            E2[idx] = __expf(p2);
            F2[idx] = __expf(0.2f * p2);
        }
    }
}

// ---- Kernel C: 32-i waves, 64-j steps, pure-gload_lds vmcnt pipeline, no barriers ----
// grid (128, 2): i-tile 32, j-half per block. Block 512 = 8 waves = 4 heads x 2 jsegs.
// Per wave: private 2 x 9216B LDS buf: [hP 8KB][E2 256][F2 256][bits 256].
__global__ __launch_bounds__(512, 2) void k_gat(
    const unsigned long long* __restrict__ bitsT, const char* __restrict__ hP,
    const float* __restrict__ E1, const float* __restrict__ F1,
    const float* __restrict__ E2, const float* __restrict__ F2,
    float* __restrict__ pA, float* __restrict__ pB, float* __restrict__ pDen)
{
    __shared__ __align__(16) char stage[8 * 18432];   // 144 KB
    const int i0 = (int)blockIdx.x * 32;
    const int by = (int)blockIdx.y;
    const int t = (int)threadIdx.x;
    const int w = t >> 6, lane = t & 63, il = lane & 15, q = lane >> 4;
    const int head = w & 3, jseg = w >> 2;
    const int jbase = by * 2048 + jseg * 1024;        // 16 steps of 64 j
    char* myst = stage + w * 18432;
    const char* hPh = hP + (size_t)head * HPB;
    const float* E2h = E2 + head * N_NODES;
    const float* F2h = F2 + head * N_NODES;
    const float e1a = E1[head * N_NODES + i0 + il];
    const float e1b = E1[head * N_NODES + i0 + 16 + il];
    const float f1a = F1[head * N_NODES + i0 + il];
    const float f1b = F1[head * N_NODES + i0 + 16 + il];
    f32x4 acc[4][2] = {};
    f32x4 accD[2] = {};
    short8 ones;
    #pragma unroll
    for (int e = 0; e < 8; ++e) ones[e] = (short)0x3F80;

    const int g0 = jbase >> 5;      // 32-j tile index base (2 tiles per step)
    const int c0 = jbase >> 6;      // 64-j chunk base
    // one batch = 11 gloads: 8 hP + E2 + F2 + bits
    auto issue = [&](int bs, char* dst) {
        const char* hsrc = hPh + (size_t)(g0 + bs * 2) * 4096;
        #pragma unroll
        for (int k = 0; k < 8; ++k)
            gload16(hsrc + k * 1024 + lane * 16, dst + k * 1024);
        gload4(E2h + jbase + bs * 64 + lane, dst + 8192);
        gload4(F2h + jbase + bs * 64 + lane, dst + 8448);
        gload4((const char*)(bitsT + (size_t)(c0 + bs) * N_NODES + i0) + lane * 4,
               dst + 8704);
    };
    issue(0, myst);
    #pragma unroll 2
    for (int s = 0; s < 16; ++s) {
        const int bs = (s + 1 < 16) ? s + 1 : 15;     // uniform count (tail re-stage)
        issue(bs, myst + ((s + 1) & 1) * 9216);
        asm volatile("s_waitcnt vmcnt(11)" ::: "memory");  // batch s landed
        const char* base = myst + (s & 1) * 9216;
        const unsigned long long bitsA = *(const unsigned long long*)(base + 8704 + il * 8);
        const unsigned long long bitsB = *(const unsigned long long*)(base + 8704 + 128 + il * 8);
        #pragma unroll
        for (int h = 0; h < 2; ++h) {
            const f32x4 ea = *(const f32x4*)(base + 8192 + h * 128 + q * 32);
            const f32x4 eb = *(const f32x4*)(base + 8192 + h * 128 + q * 32 + 16);
            const f32x4 fa = *(const f32x4*)(base + 8448 + h * 128 + q * 32);
            const f32x4 fb2 = *(const f32x4*)(base + 8448 + h * 128 + q * 32 + 16);
            const unsigned mA = (unsigned)(bitsA >> (h * 32 + q * 8)) & 0xffu;
            const unsigned mB = (unsigned)(bitsB >> (h * 32 + q * 8)) & 0xffu;
            short8 afA, afB;
            #pragma unroll
            for (int e = 0; e < 8; ++e) {
                const float Ev = (e < 4) ? ea[e] : eb[e - 4];
                const float Fv = (e < 4) ? fa[e] : fb2[e - 4];
                const float pa = fmaxf(e1a * Ev, f1a * Fv);
                const float pb = fmaxf(e1b * Ev, f1b * Fv);
                afA[e] = bf16b(((mA >> e) & 1u) ? pa : 0.f);
                afB[e] = bf16b(((mB >> e) & 1u) ? pb : 0.f);
            }
            #pragma unroll
            for (int dblk = 0; dblk < 4; ++dblk) {
                const short8 bfrag = *(const short8*)(base + h * 4096 + dblk * 1024 + lane * 16);
                acc[dblk][0] = __builtin_amdgcn_mfma_f32_16x16x32_bf16(afA, bfrag, acc[dblk][0], 0, 0, 0);
                acc[dblk][1] = __builtin_amdgcn_mfma_f32_16x16x32_bf16(afB, bfrag, acc[dblk][1], 0, 0, 0);
            }
            accD[0] = __builtin_amdgcn_mfma_f32_16x16x32_bf16(afA, ones, accD[0], 0, 0, 0);
            accD[1] = __builtin_amdgcn_mfma_f32_16x16x32_bf16(afB, ones, accD[1], 0, 0, 0);
        }
    }
    // ---- epilogue: jseg-pair reduction in LDS, write partials ----
    __syncthreads();
    float* ep = (float*)stage;           // 4 waves x 2560 f32 = 40 KB
    if (jseg == 1) {
        float* dst = ep + (w - 4) * 2560;
        #pragma unroll
        for (int dblk = 0; dblk < 4; ++dblk)
            #pragma unroll
            for (int sub = 0; sub < 2; ++sub)
                #pragma unroll
                for (int r = 0; r < 4; ++r)
                    dst[(dblk * 8 + sub * 4 + r) * 64 + lane] = acc[dblk][sub][r];
        #pragma unroll
        for (int sub = 0; sub < 2; ++sub)
            #pragma unroll
            for (int r = 0; r < 4; ++r)
                dst[(32 + sub * 4 + r) * 64 + lane] = accD[sub][r];
    }
    __syncthreads();
    if (jseg == 0) {
        const float* src = ep + w * 2560;
        float* po = (by == 0) ? pA : pB;
        #pragma unroll
        for (int sub = 0; sub < 2; ++sub) {
            #pragma unroll
            for (int r = 0; r < 4; ++r) {
                const int row = i0 + sub * 16 + q * 4 + r;   // C/D: row=(lane>>4)*4+reg
                #pragma unroll
                for (int dblk = 0; dblk < 4; ++dblk) {
                    const float v = acc[dblk][sub][r] + src[(dblk * 8 + sub * 4 + r) * 64 + lane];
                    po[(size_t)row * OUT_COLS + head * DHEAD + dblk * 16 + il] = v;
                }
                if (il == 0) {
                    const float d = accD[sub][r] + src[(32 + sub * 4 + r) * 64 + lane];
                    pDen[by * (NHEADS * N_NODES) + head * N_NODES + row] = d;
                }
            }
        }
    }
}

// ---- Kernel F: combine 2 j-half partials, divide, bias ----
__global__ __launch_bounds__(256) void k_fin(
    const float* __restrict__ pB, const float* __restrict__ pDen,
    const float* __restrict__ bias, float* __restrict__ outp)
{
    const int gid = (int)blockIdx.x * 256 + (int)threadIdx.x;  // 262144
    const int i = gid >> 6;
    const int c4 = (gid & 63) << 2;
    const int head = c4 >> 6;
    const float4 v0 = *(const float4*)(outp + (size_t)i * OUT_COLS + c4);
    const float4 v1 = *(const float4*)(pB + (size_t)i * OUT_COLS + c4);
    const float d = pDen[head * N_NODES + i] + pDen[NHEADS * N_NODES + head * N_NODES + i];
    const float inv = 1.0f / d;
    const float4 bb = *(const float4*)(bias + c4);
    float4 r;
    r.x = (v0.x + v1.x) * inv + bb.x;
    r.y = (v0.y + v1.y) * inv + bb.y;
    r.z = (v0.z + v1.z) * inv + bb.z;
    r.w = (v0.w + v1.w) * inv + bb.w;
    *(float4*)(outp + (size_t)i * OUT_COLS + c4) = r;
}

extern "C" void kernel_launch(void* const* d_in, const int* in_sizes, int n_in,
                              void* d_out, int out_size, void* d_ws, size_t ws_size,
                              hipStream_t stream) {
    const float* features  = (const float*)d_in[0];
    const int*   adjacency = (const int*)d_in[1];
    const float* weights   = (const float*)d_in[2];
    const float* attention = (const float*)d_in[3];
    const float* bias      = (const float*)d_in[4];
    float* out = (float*)d_out;

    char* ws = (char*)d_ws;
    char*  hP = ws;                                              // 2 MB
    float* E1 = (float*)(ws + 2u*1024*1024);                     // 64 KB
    float* F1 = (float*)(ws + 2u*1024*1024 +  64u*1024);
    float* E2 = (float*)(ws + 2u*1024*1024 + 128u*1024);
    float* F2 = (float*)(ws + 2u*1024*1024 + 192u*1024);
    unsigned long long* bitsT =
        (unsigned long long*)(ws + 2u*1024*1024 + 256u*1024);    // 2 MB
    float* pB   = (float*)(ws + 4u*1024*1024 + 256u*1024);       // 4 MB
    float* pDen = (float*)(ws + 8u*1024*1024 + 256u*1024);       // 128 KB

    k_prep2<<<dim3(1536), 256, 0, stream>>>(features, weights, attention, adjacency,
                                            hP, E1, F1, E2, F2, bitsT);
    k_gat<<<dim3(128, 2), 512, 0, stream>>>(bitsT, hP, E1, F1, E2, F2,
                                            out /*pA*/, pB, pDen);
    k_fin<<<dim3(1024), 256, 0, stream>>>(pB, pDen, bias, out);
}

// Round 8
// 58.596 us; speedup vs baseline: 1.4933x; 1.0053x over previous
//
#include <hip/hip_runtime.h>
#include <hip/hip_bf16.h>

#define N_NODES 4096
#define IN_DIMC 512
#define NHEADS 4
#define DHEAD 64
#define OUT_COLS 256  // NHEADS*DHEAD
#define HPB (N_NODES * DHEAD * 2)  // 512 KB per head

typedef __attribute__((ext_vector_type(8))) short short8;
typedef __attribute__((ext_vector_type(4))) float f32x4;

__device__ __forceinline__ short bf16b(float x) {
    return __builtin_bit_cast(short, __float2bfloat16(x));
}
__device__ __forceinline__ void gload16(const void* g, void* l) {
    __builtin_amdgcn_global_load_lds((const __attribute__((address_space(1))) void*)g,
                                     (__attribute__((address_space(3))) void*)l,
                                     16, 0, 0);
}
__device__ __forceinline__ void gload4(const void* g, void* l) {
    __builtin_amdgcn_global_load_lds((const __attribute__((address_space(1))) void*)g,
                                     (__attribute__((address_space(3))) void*)l,
                                     4, 0, 0);
}

// ---- Kernel A: fused {h-GEMM + hP/exp-table epilogue} and {adjacency bitpack} ----
// grid 1536: blocks [0,512) gemm (128 m-tiles x 4 heads); [512,1536) pack.
__global__ __launch_bounds__(256) void k_prep2(
    const float* __restrict__ A, const float* __restrict__ W,
    const float* __restrict__ att, const int* __restrict__ adj,
    char* __restrict__ hP, float* __restrict__ E1, float* __restrict__ F1,
    float* __restrict__ E2, float* __restrict__ F2,
    unsigned long long* __restrict__ bitsT)
{
    const int t = (int)threadIdx.x;
    if (blockIdx.x >= 512) {
        // ---- pack: row i per wave, 64 chunk-words, ILP 4 ----
        const int pb = (int)blockIdx.x - 512;
        const int i = pb * 4 + (t >> 6);       // 0..4095
        const int lane = t & 63;
        const int* arow = adj + (size_t)i * N_NODES;
        #pragma unroll 2
        for (int it = 0; it < 16; ++it) {
            const int c = it * 4;
            const int a0 = arow[(c + 0) * 64 + lane];
            const int a1 = arow[(c + 1) * 64 + lane];
            const int a2 = arow[(c + 2) * 64 + lane];
            const int a3 = arow[(c + 3) * 64 + lane];
            const unsigned long long m0 = __ballot(a0 != 0);
            const unsigned long long m1 = __ballot(a1 != 0);
            const unsigned long long m2 = __ballot(a2 != 0);
            const unsigned long long m3 = __ballot(a3 != 0);
            if (lane == 0) {
                bitsT[(size_t)(c + 0) * N_NODES + i] = m0;
                bitsT[(size_t)(c + 1) * N_NODES + i] = m1;
                bitsT[(size_t)(c + 2) * N_NODES + i] = m2;
                bitsT[(size_t)(c + 3) * N_NODES + i] = m3;
            }
        }
        return;
    }
    // ---- gemm: tile 32(nodes) x 64(d) = one head slice ----
    __shared__ float As[32][36];
    __shared__ float Bs[32][68];
    __shared__ float ht[64][33];
    const int m0 = ((int)blockIdx.x & 127) * 32;
    const int head = (int)blockIdx.x >> 7;
    const int n0 = head * 64;
    const int tm = t & 7, tn = t >> 3;
    float acc[4][2] = {};
    for (int k0 = 0; k0 < IN_DIMC; k0 += 32) {
        {
            const int r = t >> 3, kc = (t & 7) << 2;
            float4 v0 = *(const float4*)(A + (size_t)(m0 + r) * IN_DIMC + k0 + kc);
            As[kc + 0][r] = v0.x; As[kc + 1][r] = v0.y; As[kc + 2][r] = v0.z; As[kc + 3][r] = v0.w;
            const int rb = t >> 4, nc = (t & 15) << 2;
            float4 w0 = *(const float4*)(W + (size_t)(k0 + rb) * OUT_COLS + n0 + nc);
            float4 w1 = *(const float4*)(W + (size_t)(k0 + rb + 16) * OUT_COLS + n0 + nc);
            *(float4*)&Bs[rb][nc] = w0;
            *(float4*)&Bs[rb + 16][nc] = w1;
        }
        __syncthreads();
        #pragma unroll
        for (int kk = 0; kk < 32; ++kk) {
            const f32x4 a = *(const f32x4*)&As[kk][tm << 2];
            const float b0 = Bs[kk][tn * 2], b1 = Bs[kk][tn * 2 + 1];
            #pragma unroll
            for (int i = 0; i < 4; ++i) {
                acc[i][0] = fmaf(a[i], b0, acc[i][0]);
                acc[i][1] = fmaf(a[i], b1, acc[i][1]);
            }
        }
        __syncthreads();
    }
    #pragma unroll
    for (int i = 0; i < 4; ++i) {
        ht[tn * 2 + 0][(tm << 2) + i] = acc[i][0];
        ht[tn * 2 + 1][(tm << 2) + i] = acc[i][1];
    }
    __syncthreads();
    {   // packed hP: (d,j) -> 16B-slot ((g*4 + d/16)*64 + q*16 + d%16), g=j/32
        const int d = t >> 2, qq = t & 3;
        short8 hv;
        #pragma unroll
        for (int k = 0; k < 8; ++k) hv[k] = bf16b(ht[d][qq * 8 + k]);
        const size_t off16 = ((size_t)(m0 >> 5) * 4 + (d >> 4)) * 64 + qq * 16 + (d & 15);
        *(short8*)(hP + (size_t)head * HPB + off16 * 16) = hv;
    }
    {   // s1/s2 -> exp tables
        const int r = t >> 3, part = t & 7;
        float p1 = 0.f, p2 = 0.f;
        #pragma unroll
        for (int dd = 0; dd < 8; ++dd) {
            const int d = part * 8 + dd;
            const float v = ht[d][r];
            p1 = fmaf(v, att[head * 128 + d], p1);
            p2 = fmaf(v, att[head * 128 + 64 + d], p2);
        }
        p1 += __shfl_xor(p1, 1); p1 += __shfl_xor(p1, 2); p1 += __shfl_xor(p1, 4);
        p2 += __shfl_xor(p2, 1); p2 += __shfl_xor(p2, 2); p2 += __shfl_xor(p2, 4);
        if (part == 0) {
            const int idx = head * N_NODES + m0 + r;
            E1[idx] = __expf(p1);
            F1[idx] = __expf(0.2f * p1);
            E2[idx] = __expf(p2);
            F2[idx] = __expf(0.2f * p2);
        }
    }
}

// ---- Kernel C: 32-i waves, 64-j steps, pure-gload_lds vmcnt pipeline, no barriers ----
// grid (128, 2): i-tile 32, j-half per block. Block 512 = 8 waves = 4 heads x 2 jsegs.
// Per wave: private 2 x 9216B LDS buf: [hP 8KB][E2 256][F2 256][bits 256].
__global__ __launch_bounds__(512, 2) void k_gat(
    const unsigned long long* __restrict__ bitsT, const char* __restrict__ hP,
    const float* __restrict__ E1, const float* __restrict__ F1,
    const float* __restrict__ E2, const float* __restrict__ F2,
    float* __restrict__ pA, float* __restrict__ pB, float* __restrict__ pDen)
{
    __shared__ __align__(16) char stage[8 * 18432];   // 144 KB
    const int i0 = (int)blockIdx.x * 32;
    const int by = (int)blockIdx.y;
    const int t = (int)threadIdx.x;
    const int w = t >> 6, lane = t & 63, il = lane & 15, q = lane >> 4;
    const int head = w & 3, jseg = w >> 2;
    const int jbase = by * 2048 + jseg * 1024;        // 16 steps of 64 j
    char* myst = stage + w * 18432;
    const char* hPh = hP + (size_t)head * HPB;
    const float* E2h = E2 + head * N_NODES;
    const float* F2h = F2 + head * N_NODES;
    const float e1a = E1[head * N_NODES + i0 + il];
    const float e1b = E1[head * N_NODES + i0 + 16 + il];
    const float f1a = F1[head * N_NODES + i0 + il];
    const float f1b = F1[head * N_NODES + i0 + 16 + il];
    f32x4 acc[4][2] = {};
    f32x4 accD[2] = {};
    short8 ones;
    #pragma unroll
    for (int e = 0; e < 8; ++e) ones[e] = (short)0x3F80;

    const int g0 = jbase >> 5;      // 32-j tile index base (2 tiles per step)
    const int c0 = jbase >> 6;      // 64-j chunk base
    // one batch = 11 gloads: 8 hP + E2 + F2 + bits
    auto issue = [&](int bs, char* dst) {
        const char* hsrc = hPh + (size_t)(g0 + bs * 2) * 4096;
        #pragma unroll
        for (int k = 0; k < 8; ++k)
            gload16(hsrc + k * 1024 + lane * 16, dst + k * 1024);
        gload4(E2h + jbase + bs * 64 + lane, dst + 8192);
        gload4(F2h + jbase + bs * 64 + lane, dst + 8448);
        gload4((const char*)(bitsT + (size_t)(c0 + bs) * N_NODES + i0) + lane * 4,
               dst + 8704);
    };
    issue(0, myst);
    #pragma unroll 2
    for (int s = 0; s < 16; ++s) {
        const int bs = (s + 1 < 16) ? s + 1 : 15;     // uniform count (tail re-stage)
        issue(bs, myst + ((s + 1) & 1) * 9216);
        asm volatile("s_waitcnt vmcnt(11)" ::: "memory");  // batch s landed
        const char* base = myst + (s & 1) * 9216;
        const unsigned long long bitsA = *(const unsigned long long*)(base + 8704 + il * 8);
        const unsigned long long bitsB = *(const unsigned long long*)(base + 8704 + 128 + il * 8);
        #pragma unroll
        for (int h = 0; h < 2; ++h) {
            const f32x4 ea = *(const f32x4*)(base + 8192 + h * 128 + q * 32);
            const f32x4 eb = *(const f32x4*)(base + 8192 + h * 128 + q * 32 + 16);
            const f32x4 fa = *(const f32x4*)(base + 8448 + h * 128 + q * 32);
            const f32x4 fb2 = *(const f32x4*)(base + 8448 + h * 128 + q * 32 + 16);
            const unsigned mA = (unsigned)(bitsA >> (h * 32 + q * 8)) & 0xffu;
            const unsigned mB = (unsigned)(bitsB >> (h * 32 + q * 8)) & 0xffu;
            short8 afA, afB;
            #pragma unroll
            for (int e = 0; e < 8; ++e) {
                const float Ev = (e < 4) ? ea[e] : eb[e - 4];
                const float Fv = (e < 4) ? fa[e] : fb2[e - 4];
                const float pa = fmaxf(e1a * Ev, f1a * Fv);
                const float pb = fmaxf(e1b * Ev, f1b * Fv);
                afA[e] = bf16b(((mA >> e) & 1u) ? pa : 0.f);
                afB[e] = bf16b(((mB >> e) & 1u) ? pb : 0.f);
            }
            #pragma unroll
            for (int dblk = 0; dblk < 4; ++dblk) {
                const short8 bfrag = *(const short8*)(base + h * 4096 + dblk * 1024 + lane * 16);
                acc[dblk][0] = __builtin_amdgcn_mfma_f32_16x16x32_bf16(afA, bfrag, acc[dblk][0], 0, 0, 0);
                acc[dblk][1] = __builtin_amdgcn_mfma_f32_16x16x32_bf16(afB, bfrag, acc[dblk][1], 0, 0, 0);
            }
            accD[0] = __builtin_amdgcn_mfma_f32_16x16x32_bf16(afA, ones, accD[0], 0, 0, 0);
            accD[1] = __builtin_amdgcn_mfma_f32_16x16x32_bf16(afB, ones, accD[1], 0, 0, 0);
        }
    }
    // ---- epilogue: jseg-pair reduction in LDS, write partials ----
    __syncthreads();
    float* ep = (float*)stage;           // 4 waves x 2560 f32 = 40 KB
    if (jseg == 1) {
        float* dst = ep + (w - 4) * 2560;
        #pragma unroll
        for (int dblk = 0; dblk < 4; ++dblk)
            #pragma unroll
            for (int sub = 0; sub < 2; ++sub)
                #pragma unroll
                for (int r = 0; r < 4; ++r)
                    dst[(dblk * 8 + sub * 4 + r) * 64 + lane] = acc[dblk][sub][r];
        #pragma unroll
        for (int sub = 0; sub < 2; ++sub)
            #pragma unroll
            for (int r = 0; r < 4; ++r)
                dst[(32 + sub * 4 + r) * 64 + lane] = accD[sub][r];
    }
    __syncthreads();
    if (jseg == 0) {
        const float* src = ep + w * 2560;
        float* po = (by == 0) ? pA : pB;
        #pragma unroll
        for (int sub = 0; sub < 2; ++sub) {
            #pragma unroll
            for (int r = 0; r < 4; ++r) {
                const int row = i0 + sub * 16 + q * 4 + r;   // C/D: row=(lane>>4)*4+reg
                #pragma unroll
                for (int dblk = 0; dblk < 4; ++dblk) {
                    const float v = acc[dblk][sub][r] + src[(dblk * 8 + sub * 4 + r) * 64 + lane];
                    po[(size_t)row * OUT_COLS + head * DHEAD + dblk * 16 + il] = v;
                }
                if (il == 0) {
                    const float d = accD[sub][r] + src[(32 + sub * 4 + r) * 64 + lane];
                    pDen[by * (NHEADS * N_NODES) + head * N_NODES + row] = d;
                }
            }
        }
    }
}

// ---- Kernel F: combine 2 j-half partials, divide, bias ----
__global__ __launch_bounds__(256) void k_fin(
    const float* __restrict__ pB, const float* __restrict__ pDen,
    const float* __restrict__ bias, float* __restrict__ outp)
{
    const int gid = (int)blockIdx.x * 256 + (int)threadIdx.x;  // 262144
    const int i = gid >> 6;
    const int c4 = (gid & 63) << 2;
    const int head = c4 >> 6;
    const float4 v0 = *(const float4*)(outp + (size_t)i * OUT_COLS + c4);
    const float4 v1 = *(const float4*)(pB + (size_t)i * OUT_COLS + c4);
    const float d = pDen[head * N_NODES + i] + pDen[NHEADS * N_NODES + head * N_NODES + i];
    const float inv = 1.0f / d;
    const float4 bb = *(const float4*)(bias + c4);
    float4 r;
    r.x = (v0.x + v1.x) * inv + bb.x;
    r.y = (v0.y + v1.y) * inv + bb.y;
    r.z = (v0.z + v1.z) * inv + bb.z;
    r.w = (v0.w + v1.w) * inv + bb.w;
    *(float4*)(outp + (size_t)i * OUT_COLS + c4) = r;
}

extern "C" void kernel_launch(void* const* d_in, const int* in_sizes, int n_in,
                              void* d_out, int out_size, void* d_ws, size_t ws_size,
                              hipStream_t stream) {
    const float* features  = (const float*)d_in[0];
    const int*   adjacency = (const int*)d_in[1];
    const float* weights   = (const float*)d_in[2];
    const float* attention = (const float*)d_in[3];
    const float* bias      = (const float*)d_in[4];
    float* out = (float*)d_out;

    char* ws = (char*)d_ws;
    char*  hP = ws;                                              // 2 MB
    float* E1 = (float*)(ws + 2u*1024*1024);                     // 64 KB
    float* F1 = (float*)(ws + 2u*1024*1024 +  64u*1024);
    float* E2 = (float*)(ws + 2u*1024*1024 + 128u*1024);
    float* F2 = (float*)(ws + 2u*1024*1024 + 192u*1024);
    unsigned long long* bitsT =
        (unsigned long long*)(ws + 2u*1024*1024 + 256u*1024);    // 2 MB
    float* pB   = (float*)(ws + 4u*1024*1024 + 256u*1024);       // 4 MB
    float* pDen = (float*)(ws + 8u*1024*1024 + 256u*1024);       // 128 KB

    k_prep2<<<dim3(1536), 256, 0, stream>>>(features, weights, attention, adjacency,
                                            hP, E1, F1, E2, F2, bitsT);
    k_gat<<<dim3(128, 2), 512, 0, stream>>>(bitsT, hP, E1, F1, E2, F2,
                                            out /*pA*/, pB, pDen);
    k_fin<<<dim3(1024), 256, 0, stream>>>(pB, pDen, bias, out);
}